// Round 13
// baseline (331.952 us; speedup 1.0000x reference)
//
#include <hip/hip_runtime.h>
#include <hip/hip_fp16.h>

constexpr int FIN   = 128;   // input features (also total hidden width)
constexpr int HH    = 64;    // half hidden (GCN branch width)
constexpr int NPB   = 256;   // nodes per bucket (bucket = col >> 8)
constexpr int MAXNB = 512;   // max buckets supported (N <= 131072)
constexpr int BCH   = 2048;  // edges per k_bin block (2048: 25KB LDS -> 6 blk/CU)
constexpr int BCAP  = 4608;  // bucket stride in binned[] (Poisson(4096)+8s)
constexpr int CAPB  = 4500;  // LDS stage capacity in k_place

typedef _Float16 half4v __attribute__((ext_vector_type(4)));

// ------------------------------------------------------------------ GEMM ----
// xw[N,128] = x[N,128] @ [W1 | Wf1]   (W1,Wf1 are [128,64] row-major)
// also writes xwh[N,64] = fp16 copy of the GCN half (cols 0..63) for gathers
__global__ __launch_bounds__(256) void k_gemm(
    const float* __restrict__ x, const float* __restrict__ W1,
    const float* __restrict__ Wf1, float* __restrict__ xw,
    _Float16* __restrict__ xwh, int N)
{
    __shared__ float xs[16][68];     // [k][node], +4 pad
    __shared__ float ws[16][128];    // [k][col]

    const int tid = threadIdx.x;
    const int tx  = tid & 31;        // col group: cols tx*4 .. tx*4+3
    const int ty  = tid >> 5;        // node group: nodes ty*8 .. ty*8+7
    const int nbase = blockIdx.x * 64;

    float acc[8][4];
#pragma unroll
    for (int i = 0; i < 8; ++i)
#pragma unroll
        for (int j = 0; j < 4; ++j) acc[i][j] = 0.0f;

    const int xr_row = tid >> 2;
    const int xr_kk0 = (tid & 3) * 4;
    int nload = nbase + xr_row;
    const int nclamped = (nload < N) ? nload : (N - 1);

    const int wk = tid >> 4;
    const int wc = (tid * 8) & 127;

    for (int k0 = 0; k0 < FIN; k0 += 16) {
        float4 xv = *(const float4*)(x + (size_t)nclamped * FIN + k0 + xr_kk0);
        xs[xr_kk0 + 0][xr_row] = xv.x;
        xs[xr_kk0 + 1][xr_row] = xv.y;
        xs[xr_kk0 + 2][xr_row] = xv.z;
        xs[xr_kk0 + 3][xr_row] = xv.w;
        {
            const float* src = (wc < HH) ? (W1  + (size_t)(k0 + wk) * HH + wc)
                                         : (Wf1 + (size_t)(k0 + wk) * HH + (wc - HH));
            float4 w0 = *(const float4*)(src);
            float4 w1 = *(const float4*)(src + 4);
            *(float4*)&ws[wk][wc]     = w0;
            *(float4*)&ws[wk][wc + 4] = w1;
        }
        __syncthreads();

#pragma unroll
        for (int kk = 0; kk < 16; ++kk) {
            float4 xa = *(const float4*)&xs[kk][ty * 8];
            float4 xb = *(const float4*)&xs[kk][ty * 8 + 4];
            float4 wv = *(const float4*)&ws[kk][tx * 4];
            float xr[8] = {xa.x, xa.y, xa.z, xa.w, xb.x, xb.y, xb.z, xb.w};
#pragma unroll
            for (int i = 0; i < 8; ++i) {
                acc[i][0] = fmaf(xr[i], wv.x, acc[i][0]);
                acc[i][1] = fmaf(xr[i], wv.y, acc[i][1]);
                acc[i][2] = fmaf(xr[i], wv.z, acc[i][2]);
                acc[i][3] = fmaf(xr[i], wv.w, acc[i][3]);
            }
        }
        __syncthreads();
    }

#pragma unroll
    for (int i = 0; i < 8; ++i) {
        int n = nbase + ty * 8 + i;
        if (n < N) {
            float4 v = make_float4(acc[i][0], acc[i][1], acc[i][2], acc[i][3]);
            *(float4*)(xw + (size_t)n * FIN + tx * 4) = v;
            if (tx < 16) {   // GCN half -> fp16 gather copy
                half4v h;
                h[0] = (_Float16)v.x; h[1] = (_Float16)v.y;
                h[2] = (_Float16)v.z; h[3] = (_Float16)v.w;
                *(half4v*)(xwh + (size_t)n * HH + tx * 4) = h;
            }
        }
    }
}

// --------------------------------------- pass A: bin edges + degree count ---
// LDS-reorders each 2048-edge chunk by bucket (col>>8) and flushes runs to
// per-bucket regions of binned[] -> coalesced writes. Smaller chunk (2048)
// keeps LDS at 25KB -> ~3 co-resident blocks/CU for latency hiding (the 4096
// version ran at 1.5 blocks/CU, 14% occupancy, latency-bound at 82us).
__global__ __launch_bounds__(256) void k_bin(
    const int* __restrict__ ei, int* __restrict__ cnt,
    int* __restrict__ bcur, int2* __restrict__ binned, int E, int NB)
{
    __shared__ int hist[MAXNB], scur[MAXNB], gbase[MAXNB], sbase[MAXNB];
    __shared__ int ssum[256];
    __shared__ int2 st[BCH];
    const int tid = threadIdx.x;
    const int e0  = blockIdx.x * BCH;
    const int nE  = min(BCH, E - e0);

    for (int b = tid; b < NB; b += 256) hist[b] = 0;
    __syncthreads();

    for (int k = tid; k < nE; k += 256) {
        int c = ei[E + e0 + k];
        atomicAdd(&hist[c >> 8], 1);
        atomicAdd(cnt + c, 1);        // degree (replaces k_count)
    }
    __syncthreads();

    // exclusive scan hist -> sbase (2 elems/thread over padded 512)
    int h0 = (2 * tid     < NB) ? hist[2 * tid]     : 0;
    int h1 = (2 * tid + 1 < NB) ? hist[2 * tid + 1] : 0;
    ssum[tid] = h0 + h1;
    __syncthreads();
    for (int o = 1; o < 256; o <<= 1) {
        int y = (tid >= o) ? ssum[tid - o] : 0;
        __syncthreads();
        ssum[tid] += y;
        __syncthreads();
    }
    int eb = ssum[tid] - h0 - h1;
    if (2 * tid     < NB) { sbase[2 * tid]     = eb;      scur[2 * tid]     = eb; }
    if (2 * tid + 1 < NB) { sbase[2 * tid + 1] = eb + h0; scur[2 * tid + 1] = eb + h0; }
    __syncthreads();

    // claim global per-bucket ranges (one atomic per non-empty bucket)
    for (int b = tid; b < NB; b += 256)
        if (hist[b] > 0) gbase[b] = atomicAdd(bcur + b, hist[b]);

    // LDS reorder by bucket
    for (int k = tid; k < nE; k += 256) {
        int r = ei[e0 + k];
        int c = ei[E + e0 + k];
        int b = c >> 8;
        int s = atomicAdd(&scur[b], 1);
        st[s] = make_int2(r, c);
    }
    __syncthreads();

    // coalesced-run flush (bucket recomputed from col: saves the bos[] array)
    for (int s = tid; s < nE; s += 256) {
        int2 rc = st[s];
        int b = rc.y >> 8;
        long dest = (long)b * BCAP + gbase[b] + (s - sbase[b]);
        binned[dest] = rc;
    }
}

// ------------------------------------------------------------ CSR scans -----
__global__ __launch_bounds__(256) void k_scan1(
    const int* __restrict__ cnt, int* __restrict__ off, int* __restrict__ bsum, int N)
{
    __shared__ int s[256];
    const int t = threadIdx.x;
    const int idx = blockIdx.x * 1024 + t * 4;
    int v[4]; int mysum = 0;
#pragma unroll
    for (int j = 0; j < 4; ++j) {
        v[j] = (idx + j < N) ? cnt[idx + j] : 0;
        mysum += v[j];
    }
    s[t] = mysum;
    __syncthreads();
    for (int o = 1; o < 256; o <<= 1) {
        int y = (t >= o) ? s[t - o] : 0;
        __syncthreads();
        s[t] += y;
        __syncthreads();
    }
    int running = s[t] - mysum;
#pragma unroll
    for (int j = 0; j < 4; ++j) {
        if (idx + j < N) off[idx + j] = running;
        running += v[j];
    }
    if (t == 255) bsum[blockIdx.x] = s[255];
}

__global__ void k_scan2(int* __restrict__ bsum, int nb) {
    if (threadIdx.x == 0 && blockIdx.x == 0) {
        int run = 0;
        for (int i = 0; i < nb; ++i) { int v = bsum[i]; bsum[i] = run; run += v; }
    }
}

// add block offsets; dinv = rsqrt(cnt+1)  (self-loop incl.)
__global__ void k_scan3(const int* __restrict__ cnt, int* __restrict__ off,
                        const int* __restrict__ bsum, float* __restrict__ dinv, int N)
{
    int i = blockIdx.x * blockDim.x + threadIdx.x;
    if (i < N) {
        off[i] += bsum[i >> 10];
        dinv[i] = rsqrtf((float)cnt[i] + 1.0f);
    }
}

// ----------------------- pass B: per-bucket LDS scatter, coalesced write ----
// one block per bucket; bucket's sedge region is built in LDS (per-node
// counters), then copied out linearly -> writeback ~= payload (13 MB).
__global__ __launch_bounds__(256) void k_place(
    const int2* __restrict__ binned, const int* __restrict__ bcur,
    const int* __restrict__ off, const float* __restrict__ dinv,
    int2* __restrict__ sedge, int N)
{
    const int b   = blockIdx.x;
    const int tid = threadIdx.x;
    const int nlo = b << 8;
    const int nn  = min(NPB, N - nlo);
    __shared__ int  loff[NPB];
    __shared__ int  lcnt[NPB];
    __shared__ int2 stage[CAPB];
    const int base = off[nlo];
    if (tid < nn) { loff[tid] = off[nlo + tid] - base; lcnt[tid] = 0; }
    __syncthreads();
    const int ke = bcur[b];
    const int2* src = binned + (long)b * BCAP;
    if (ke <= CAPB) {
        for (int k = tid; k < ke; k += 256) {
            int2 rc = src[k];
            float nrm = dinv[rc.x] * dinv[rc.y];
            int li = rc.y - nlo;
            int p = atomicAdd(&lcnt[li], 1);
            stage[loff[li] + p] = make_int2(rc.x, __float_as_int(nrm));
        }
        __syncthreads();
        for (int s = tid; s < ke; s += 256) sedge[base + s] = stage[s];
    } else {   // statistically impossible overflow fallback: direct scatter
        for (int k = tid; k < ke; k += 256) {
            int2 rc = src[k];
            float nrm = dinv[rc.x] * dinv[rc.y];
            int li = rc.y - nlo;
            int p = atomicAdd(&lcnt[li], 1);
            sedge[base + loff[li] + p] = make_int2(rc.x, __float_as_int(nrm));
        }
    }
}

// ------------------------- fused: layer-1 aggregate + relu + layer-2 dots ---
// one wave per node; 4 groups of 16 lanes process edges, 2 gathers in flight
// per group per iteration (8 edges/wave/iter); lanes load half4 fp16.
__global__ __launch_bounds__(256) void k_fused(
    const int* __restrict__ off, const int* __restrict__ cnt,
    const int2* __restrict__ sedge, const float* __restrict__ dinv,
    const float* __restrict__ xw, const _Float16* __restrict__ xwh,
    const float* __restrict__ b1, const float* __restrict__ bf1,
    const float* __restrict__ W2, const float* __restrict__ Wf2,
    const float* __restrict__ b2, const float* __restrict__ bf2,
    float* __restrict__ z, float* __restrict__ out, int N)
{
    const int wid  = (blockIdx.x * blockDim.x + threadIdx.x) >> 6;  // node id
    const int lane = threadIdx.x & 63;
    const int g    = lane >> 4;        // edge group 0..3
    const int l16  = lane & 15;        // feature quad: features l16*4..+3
    const int i    = (wid < N) ? wid : (N - 1);

    const int jb  = off[i];
    const int deg = cnt[i];

    // one coalesced load grabs the whole edge list (deg <= 64 virtually always)
    int2 er = make_int2(i, 0);
    if (lane < deg) er = sedge[jb + lane];

    float4 acc = make_float4(0.f, 0.f, 0.f, 0.f);
    const int lim = (deg < 64) ? deg : 64;
    for (int t0 = 0; t0 < lim; t0 += 8) {
        int  ttA   = t0 + g;
        int  ttB   = t0 + 4 + g;
        bool vA    = ttA < lim;
        bool vB    = ttB < lim;
        int  rowA  = __shfl(er.x, ttA, 64);
        int  nrmA  = __shfl(er.y, ttA, 64);
        int  rowB  = __shfl(er.x, ttB, 64);
        int  nrmB  = __shfl(er.y, ttB, 64);
        rowA       = vA ? rowA : i;
        rowB       = vB ? rowB : i;
        float sA   = vA ? __int_as_float(nrmA) : 0.0f;
        float sB   = vB ? __int_as_float(nrmB) : 0.0f;
        half4v a = *(const half4v*)(xwh + (size_t)rowA * HH + l16 * 4);
        half4v b = *(const half4v*)(xwh + (size_t)rowB * HH + l16 * 4);
        acc.x = fmaf((float)a[0], sA, acc.x);
        acc.y = fmaf((float)a[1], sA, acc.y);
        acc.z = fmaf((float)a[2], sA, acc.z);
        acc.w = fmaf((float)a[3], sA, acc.w);
        acc.x = fmaf((float)b[0], sB, acc.x);
        acc.y = fmaf((float)b[1], sB, acc.y);
        acc.z = fmaf((float)b[2], sB, acc.z);
        acc.w = fmaf((float)b[3], sB, acc.w);
    }
    // rare tail: deg > 64
    for (int j = jb + 64 + g; j < jb + deg; j += 4) {
        int2 ep = sedge[j];
        float s = __int_as_float(ep.y);
        half4v v = *(const half4v*)(xwh + (size_t)ep.x * HH + l16 * 4);
        acc.x = fmaf((float)v[0], s, acc.x);
        acc.y = fmaf((float)v[1], s, acc.y);
        acc.z = fmaf((float)v[2], s, acc.z);
        acc.w = fmaf((float)v[3], s, acc.w);
    }

    // combine the 4 edge-groups
    acc.x += __shfl_xor(acc.x, 16, 64); acc.x += __shfl_xor(acc.x, 32, 64);
    acc.y += __shfl_xor(acc.y, 16, 64); acc.y += __shfl_xor(acc.y, 32, 64);
    acc.z += __shfl_xor(acc.z, 16, 64); acc.z += __shfl_xor(acc.z, 32, 64);
    acc.w += __shfl_xor(acc.w, 16, 64); acc.w += __shfl_xor(acc.w, 32, 64);

    // self loop (fp32, exact)
    float di = dinv[i];
    float dd = di * di;
    float4 sv = *(const float4*)(xw + (size_t)i * FIN + l16 * 4);
    acc.x = fmaf(sv.x, dd, acc.x);
    acc.y = fmaf(sv.y, dd, acc.y);
    acc.z = fmaf(sv.z, dd, acc.z);
    acc.w = fmaf(sv.w, dd, acc.w);

    // epilogue: relu + two 128-dots
    float4 b1v  = *(const float4*)(b1  + l16 * 4);
    float4 bf1v = *(const float4*)(bf1 + l16 * 4);
    float4 x1   = *(const float4*)(xw + (size_t)i * FIN + HH + l16 * 4);
    float4 h0, h1;
    h0.x = fmaxf(acc.x + b1v.x, 0.f);  h0.y = fmaxf(acc.y + b1v.y, 0.f);
    h0.z = fmaxf(acc.z + b1v.z, 0.f);  h0.w = fmaxf(acc.w + b1v.w, 0.f);
    h1.x = fmaxf(x1.x + bf1v.x, 0.f);  h1.y = fmaxf(x1.y + bf1v.y, 0.f);
    h1.z = fmaxf(x1.z + bf1v.z, 0.f);  h1.w = fmaxf(x1.w + bf1v.w, 0.f);

    float4 w2a  = *(const float4*)(W2  + l16 * 4);
    float4 w2b  = *(const float4*)(W2  + HH + l16 * 4);
    float4 wf2a = *(const float4*)(Wf2 + l16 * 4);
    float4 wf2b = *(const float4*)(Wf2 + HH + l16 * 4);

    float zp = h0.x * w2a.x + h0.y * w2a.y + h0.z * w2a.z + h0.w * w2a.w
             + h1.x * w2b.x + h1.y * w2b.y + h1.z * w2b.z + h1.w * w2b.w;
    float fp = h0.x * wf2a.x + h0.y * wf2a.y + h0.z * wf2a.z + h0.w * wf2a.w
             + h1.x * wf2b.x + h1.y * wf2b.y + h1.z * wf2b.z + h1.w * wf2b.w;
#pragma unroll
    for (int o = 8; o > 0; o >>= 1) {
        zp += __shfl_xor(zp, o, 64);
        fp += __shfl_xor(fp, o, 64);
    }
    if (lane == 0 && wid < N) {
        z[i]   = zp;
        out[i] = fp + b2[0] + bf2[0];
    }
}

// ------------------------------------------- layer-2 aggregate (CSR) --------
__global__ __launch_bounds__(256) void k_agg2(
    const int* __restrict__ off, const int* __restrict__ cnt,
    const int2* __restrict__ sedge, const float* __restrict__ dinv,
    const float* __restrict__ z, float* __restrict__ out, int N)
{
    const int wid  = (blockIdx.x * blockDim.x + threadIdx.x) >> 6;
    const int lane = threadIdx.x & 63;
    const int g    = lane >> 4;
    const int l16  = lane & 15;
    int i = wid * 4 + g;
    bool ok = (i < N);
    i = ok ? i : (N - 1);

    const int jb = off[i], je = jb + cnt[i];
    float s = 0.0f;
    for (int j = jb + l16; j < je; j += 16) {
        int2 ep = sedge[j];
        s = fmaf(z[ep.x], __int_as_float(ep.y), s);
    }
#pragma unroll
    for (int o = 8; o > 0; o >>= 1) s += __shfl_xor(s, o, 64);
    if (l16 == 0 && ok) {
        float di = dinv[i];
        out[i] += fmaf(z[i], di * di, s);
    }
}

// ---------------------------------------------------------------- launch ----
extern "C" void kernel_launch(void* const* d_in, const int* in_sizes, int n_in,
                              void* d_out, int out_size, void* d_ws, size_t ws_size,
                              hipStream_t stream)
{
    const float* x   = (const float*)d_in[0];
    const int*   ei  = (const int*)d_in[1];    // [2,E]: row=ei[e], col=ei[E+e]
    const float* W1  = (const float*)d_in[2];
    const float* b1  = (const float*)d_in[3];
    const float* Wf1 = (const float*)d_in[4];
    const float* bf1 = (const float*)d_in[5];
    const float* W2  = (const float*)d_in[6];
    const float* b2  = (const float*)d_in[7];
    const float* Wf2 = (const float*)d_in[8];
    const float* bf2 = (const float*)d_in[9];

    const int N = in_sizes[0] / FIN;   // 100000
    const int E = in_sizes[1] / 2;     // 1600000
    const int NB = (N + NPB - 1) / NPB;  // 391 buckets
    float* out = (float*)d_out;

    // workspace layout (4-byte units):
    // xw[N*128] | dinv[N] | z[N] | cnt[N] | bcur[MAXNB] | off[N] | bsum[pad] |
    // sedge[E int2] | xwh[N*64 halves].  binned[NB*BCAP int2] overlays xw
    // (14.4 MB <= 51.2 MB; xw is written by k_gemm AFTER k_place consumed it).
    const int nb = (N + 1023) / 1024;
    float* ws   = (float*)d_ws;
    float* xw   = ws;
    float* dinv = xw + (size_t)N * FIN;
    float* z    = dinv + N;
    int*   cnt  = (int*)(z + N);
    int*   bcur = cnt + N;
    int*   off  = bcur + MAXNB;
    int*   bsum = off + N;
    int    bpad = (nb + 2) & ~1;
    int2*  sedge = (int2*)(bsum + bpad);
    _Float16* xwh = (_Float16*)(sedge + E);
    int2*  binned = (int2*)ws;             // overlay on xw region

    hipMemsetAsync(cnt, 0, (size_t)(N + MAXNB) * sizeof(int), stream);

    k_bin<<<(E + BCH - 1) / BCH, 256, 0, stream>>>(ei, cnt, bcur, binned, E, NB);
    k_scan1<<<nb, 256, 0, stream>>>(cnt, off, bsum, N);
    k_scan2<<<1, 64, 0, stream>>>(bsum, nb);
    k_scan3<<<(N + 255) / 256, 256, 0, stream>>>(cnt, off, bsum, dinv, N);
    k_place<<<NB, 256, 0, stream>>>(binned, bcur, off, dinv, sedge, N);

    k_gemm<<<(N + 63) / 64, 256, 0, stream>>>(x, W1, Wf1, xw, xwh, N);

    {
        long threads = (long)N * 64;           // one wave per node
        int blocks = (int)((threads + 255) / 256);
        k_fused<<<blocks, 256, 0, stream>>>(off, cnt, sedge, dinv, xw, xwh,
                                            b1, bf1, W2, Wf2, b2, bf2, z, out, N);
    }

    {
        long waves = ((long)N + 3) / 4;        // one wave per 4 nodes
        int blocks = (int)((waves * 64 + 255) / 256);
        k_agg2<<<blocks, 256, 0, stream>>>(off, cnt, sedge, dinv, z, out, N);
    }
}

// Round 14
// 274.603 us; speedup vs baseline: 1.2088x; 1.2088x over previous
//
#include <hip/hip_runtime.h>
#include <hip/hip_fp16.h>

constexpr int FIN   = 128;   // input features (also total hidden width)
constexpr int HH    = 64;    // half hidden (GCN branch width)
constexpr int NPB   = 256;   // nodes per bucket (bucket = col >> 8)
constexpr int MAXNB = 512;   // max buckets supported (N <= 131072)
constexpr int BCH   = 4096;  // edges per k_bin block (4096 measured > 2048)
constexpr int BCAP  = 4608;  // bucket stride in binned[]
constexpr int CAPB  = 4500;  // LDS stage capacity in k_place

typedef _Float16 half4v __attribute__((ext_vector_type(4)));

// ------------------------------------------------------------------ GEMM ----
__global__ __launch_bounds__(256) void k_gemm(
    const float* __restrict__ x, const float* __restrict__ W1,
    const float* __restrict__ Wf1, float* __restrict__ xw,
    _Float16* __restrict__ xwh, int N)
{
    __shared__ float xs[16][68];     // [k][node], +4 pad
    __shared__ float ws[16][128];    // [k][col]

    const int tid = threadIdx.x;
    const int tx  = tid & 31;
    const int ty  = tid >> 5;
    const int nbase = blockIdx.x * 64;

    float acc[8][4];
#pragma unroll
    for (int i = 0; i < 8; ++i)
#pragma unroll
        for (int j = 0; j < 4; ++j) acc[i][j] = 0.0f;

    const int xr_row = tid >> 2;
    const int xr_kk0 = (tid & 3) * 4;
    int nload = nbase + xr_row;
    const int nclamped = (nload < N) ? nload : (N - 1);

    const int wk = tid >> 4;
    const int wc = (tid * 8) & 127;

    for (int k0 = 0; k0 < FIN; k0 += 16) {
        float4 xv = *(const float4*)(x + (size_t)nclamped * FIN + k0 + xr_kk0);
        xs[xr_kk0 + 0][xr_row] = xv.x;
        xs[xr_kk0 + 1][xr_row] = xv.y;
        xs[xr_kk0 + 2][xr_row] = xv.z;
        xs[xr_kk0 + 3][xr_row] = xv.w;
        {
            const float* src = (wc < HH) ? (W1  + (size_t)(k0 + wk) * HH + wc)
                                         : (Wf1 + (size_t)(k0 + wk) * HH + (wc - HH));
            float4 w0 = *(const float4*)(src);
            float4 w1 = *(const float4*)(src + 4);
            *(float4*)&ws[wk][wc]     = w0;
            *(float4*)&ws[wk][wc + 4] = w1;
        }
        __syncthreads();

#pragma unroll
        for (int kk = 0; kk < 16; ++kk) {
            float4 xa = *(const float4*)&xs[kk][ty * 8];
            float4 xb = *(const float4*)&xs[kk][ty * 8 + 4];
            float4 wv = *(const float4*)&ws[kk][tx * 4];
            float xr[8] = {xa.x, xa.y, xa.z, xa.w, xb.x, xb.y, xb.z, xb.w};
#pragma unroll
            for (int i = 0; i < 8; ++i) {
                acc[i][0] = fmaf(xr[i], wv.x, acc[i][0]);
                acc[i][1] = fmaf(xr[i], wv.y, acc[i][1]);
                acc[i][2] = fmaf(xr[i], wv.z, acc[i][2]);
                acc[i][3] = fmaf(xr[i], wv.w, acc[i][3]);
            }
        }
        __syncthreads();
    }

#pragma unroll
    for (int i = 0; i < 8; ++i) {
        int n = nbase + ty * 8 + i;
        if (n < N) {
            float4 v = make_float4(acc[i][0], acc[i][1], acc[i][2], acc[i][3]);
            *(float4*)(xw + (size_t)n * FIN + tx * 4) = v;
            if (tx < 16) {   // GCN half -> fp16 gather copy
                half4v h;
                h[0] = (_Float16)v.x; h[1] = (_Float16)v.y;
                h[2] = (_Float16)v.z; h[3] = (_Float16)v.w;
                *(half4v*)(xwh + (size_t)n * HH + tx * 4) = h;
            }
        }
    }
}

// --------------------------------------- pass A: bin edges by bucket --------
// LDS-reorders each 4096-edge chunk by bucket (col>>8) and flushes runs to
// per-bucket regions of binned[]. NO per-edge global atomics (degree counting
// moved to k_place; round-13 falsified the occupancy theory — testing the
// per-edge-atomic theory now).
__global__ __launch_bounds__(256) void k_bin(
    const int* __restrict__ ei, int* __restrict__ bcur,
    int2* __restrict__ binned, int E, int NB)
{
    __shared__ int hist[MAXNB], scur[MAXNB], gbase[MAXNB], sbase[MAXNB];
    __shared__ int ssum[256];
    __shared__ int2 st[BCH];
    const int tid = threadIdx.x;
    const int e0  = blockIdx.x * BCH;
    const int nE  = min(BCH, E - e0);

    for (int b = tid; b < NB; b += 256) hist[b] = 0;
    __syncthreads();

    for (int k = tid; k < nE; k += 256)
        atomicAdd(&hist[ei[E + e0 + k] >> 8], 1);
    __syncthreads();

    // exclusive scan hist -> sbase (2 elems/thread over padded 512)
    int h0 = (2 * tid     < NB) ? hist[2 * tid]     : 0;
    int h1 = (2 * tid + 1 < NB) ? hist[2 * tid + 1] : 0;
    ssum[tid] = h0 + h1;
    __syncthreads();
    for (int o = 1; o < 256; o <<= 1) {
        int y = (tid >= o) ? ssum[tid - o] : 0;
        __syncthreads();
        ssum[tid] += y;
        __syncthreads();
    }
    int eb = ssum[tid] - h0 - h1;
    if (2 * tid     < NB) { sbase[2 * tid]     = eb;      scur[2 * tid]     = eb; }
    if (2 * tid + 1 < NB) { sbase[2 * tid + 1] = eb + h0; scur[2 * tid + 1] = eb + h0; }
    __syncthreads();

    // claim global per-bucket ranges (one atomic per non-empty bucket)
    for (int b = tid; b < NB; b += 256)
        if (hist[b] > 0) gbase[b] = atomicAdd(bcur + b, hist[b]);

    // LDS reorder by bucket
    for (int k = tid; k < nE; k += 256) {
        int r = ei[e0 + k];
        int c = ei[E + e0 + k];
        int s = atomicAdd(&scur[c >> 8], 1);
        st[s] = make_int2(r, c);
    }
    __syncthreads();

    // coalesced-run flush (bucket recomputed from col)
    for (int s = tid; s < nE; s += 256) {
        int2 rc = st[s];
        int b = rc.y >> 8;
        long dest = (long)b * BCAP + gbase[b] + (s - sbase[b]);
        binned[dest] = rc;
    }
}

// ------------------------------------- scan bucket totals -> bucket bases ---
__global__ void k_bscan(const int* __restrict__ bcur, int* __restrict__ bbase, int NB) {
    if (threadIdx.x == 0 && blockIdx.x == 0) {
        int run = 0;
        for (int i = 0; i < NB; ++i) { bbase[i] = run; run += bcur[i]; }
    }
}

// ---------------- pass B: per-bucket degree+scan+place, coalesced write -----
// one block per bucket. Computes its 256 nodes' degree (LDS histogram over
// the bucket's binned edges), local exclusive scan -> writes cnt/off/dinv
// (replaces k_scan1/2/3 + memset(cnt)), then LDS-scatters source ids and
// flushes sedge (int: source only — norm recomputed at use) coalesced.
__global__ __launch_bounds__(256) void k_place(
    const int2* __restrict__ binned, const int* __restrict__ bcur,
    const int* __restrict__ bbase, int* __restrict__ cnt, int* __restrict__ off,
    float* __restrict__ dinv, int* __restrict__ sedge, int N)
{
    const int b   = blockIdx.x;
    const int tid = threadIdx.x;
    const int nlo = b << 8;
    const int nn  = min(NPB, N - nlo);
    __shared__ int lcnt[NPB], loff[NPB], lscan[NPB];
    __shared__ int stage[CAPB];
    lcnt[tid] = 0;
    __syncthreads();
    const int ke = bcur[b];
    const int2* src = binned + (long)b * BCAP;
    // pass 1: per-node degree
    for (int k = tid; k < ke; k += 256)
        atomicAdd(&lcnt[src[k].y - nlo], 1);
    __syncthreads();
    // exclusive scan of lcnt[256]
    int v = lcnt[tid];
    lscan[tid] = v;
    __syncthreads();
    for (int o = 1; o < 256; o <<= 1) {
        int y = (tid >= o) ? lscan[tid - o] : 0;
        __syncthreads();
        lscan[tid] += y;
        __syncthreads();
    }
    int excl = lscan[tid] - v;
    loff[tid] = excl;
    const int base = bbase[b];
    if (tid < nn) {
        cnt[nlo + tid]  = v;
        off[nlo + tid]  = base + excl;
        dinv[nlo + tid] = rsqrtf((float)v + 1.0f);
    }
    lcnt[tid] = 0;
    __syncthreads();
    // pass 2: place source ids
    if (ke <= CAPB) {
        for (int k = tid; k < ke; k += 256) {
            int2 rc = src[k];
            int li = rc.y - nlo;
            int p = atomicAdd(&lcnt[li], 1);
            stage[loff[li] + p] = rc.x;
        }
        __syncthreads();
        for (int s = tid; s < ke; s += 256) sedge[base + s] = stage[s];
    } else {   // statistically impossible overflow fallback
        for (int k = tid; k < ke; k += 256) {
            int2 rc = src[k];
            int li = rc.y - nlo;
            int p = atomicAdd(&lcnt[li], 1);
            sedge[base + loff[li] + p] = rc.x;
        }
    }
}

// ------------------------- fused: layer-1 aggregate + relu + layer-2 dots ---
// sedge holds source id only; norm = dinv[r]*dinv[i] recomputed (dinv is a
// 400KB L2-resident table; owner lane gathers dinv[r] once per edge).
__global__ __launch_bounds__(256) void k_fused(
    const int* __restrict__ off, const int* __restrict__ cnt,
    const int* __restrict__ sedge, const float* __restrict__ dinv,
    const float* __restrict__ xw, const _Float16* __restrict__ xwh,
    const float* __restrict__ b1, const float* __restrict__ bf1,
    const float* __restrict__ W2, const float* __restrict__ Wf2,
    const float* __restrict__ b2, const float* __restrict__ bf2,
    float* __restrict__ z, float* __restrict__ out, int N)
{
    const int wid  = (blockIdx.x * blockDim.x + threadIdx.x) >> 6;  // node id
    const int lane = threadIdx.x & 63;
    const int g    = lane >> 4;        // edge group 0..3
    const int l16  = lane & 15;        // feature quad
    const int i    = (wid < N) ? wid : (N - 1);

    const int jb  = off[i];
    const int deg = cnt[i];
    const float di = dinv[i];

    int   er_r = i;
    float er_d = 0.0f;
    if (lane < deg) { er_r = sedge[jb + lane]; er_d = dinv[er_r]; }

    float4 acc = make_float4(0.f, 0.f, 0.f, 0.f);
    const int lim = (deg < 64) ? deg : 64;
    for (int t0 = 0; t0 < lim; t0 += 8) {
        int  ttA   = t0 + g;
        int  ttB   = t0 + 4 + g;
        bool vA    = ttA < lim;
        bool vB    = ttB < lim;
        int   rowA = __shfl(er_r, ttA, 64);
        float dA   = __shfl(er_d, ttA, 64);
        int   rowB = __shfl(er_r, ttB, 64);
        float dB   = __shfl(er_d, ttB, 64);
        rowA       = vA ? rowA : i;
        rowB       = vB ? rowB : i;
        float sA   = vA ? dA * di : 0.0f;
        float sB   = vB ? dB * di : 0.0f;
        half4v a = *(const half4v*)(xwh + (size_t)rowA * HH + l16 * 4);
        half4v b = *(const half4v*)(xwh + (size_t)rowB * HH + l16 * 4);
        acc.x = fmaf((float)a[0], sA, acc.x);
        acc.y = fmaf((float)a[1], sA, acc.y);
        acc.z = fmaf((float)a[2], sA, acc.z);
        acc.w = fmaf((float)a[3], sA, acc.w);
        acc.x = fmaf((float)b[0], sB, acc.x);
        acc.y = fmaf((float)b[1], sB, acc.y);
        acc.z = fmaf((float)b[2], sB, acc.z);
        acc.w = fmaf((float)b[3], sB, acc.w);
    }
    // rare tail: deg > 64
    for (int j = jb + 64 + g; j < jb + deg; j += 4) {
        int rj = sedge[j];
        float s = dinv[rj] * di;
        half4v v = *(const half4v*)(xwh + (size_t)rj * HH + l16 * 4);
        acc.x = fmaf((float)v[0], s, acc.x);
        acc.y = fmaf((float)v[1], s, acc.y);
        acc.z = fmaf((float)v[2], s, acc.z);
        acc.w = fmaf((float)v[3], s, acc.w);
    }

    // combine the 4 edge-groups
    acc.x += __shfl_xor(acc.x, 16, 64); acc.x += __shfl_xor(acc.x, 32, 64);
    acc.y += __shfl_xor(acc.y, 16, 64); acc.y += __shfl_xor(acc.y, 32, 64);
    acc.z += __shfl_xor(acc.z, 16, 64); acc.z += __shfl_xor(acc.z, 32, 64);
    acc.w += __shfl_xor(acc.w, 16, 64); acc.w += __shfl_xor(acc.w, 32, 64);

    // self loop (fp32, exact)
    float dd = di * di;
    float4 sv = *(const float4*)(xw + (size_t)i * FIN + l16 * 4);
    acc.x = fmaf(sv.x, dd, acc.x);
    acc.y = fmaf(sv.y, dd, acc.y);
    acc.z = fmaf(sv.z, dd, acc.z);
    acc.w = fmaf(sv.w, dd, acc.w);

    // epilogue: relu + two 128-dots
    float4 b1v  = *(const float4*)(b1  + l16 * 4);
    float4 bf1v = *(const float4*)(bf1 + l16 * 4);
    float4 x1   = *(const float4*)(xw + (size_t)i * FIN + HH + l16 * 4);
    float4 h0, h1;
    h0.x = fmaxf(acc.x + b1v.x, 0.f);  h0.y = fmaxf(acc.y + b1v.y, 0.f);
    h0.z = fmaxf(acc.z + b1v.z, 0.f);  h0.w = fmaxf(acc.w + b1v.w, 0.f);
    h1.x = fmaxf(x1.x + bf1v.x, 0.f);  h1.y = fmaxf(x1.y + bf1v.y, 0.f);
    h1.z = fmaxf(x1.z + bf1v.z, 0.f);  h1.w = fmaxf(x1.w + bf1v.w, 0.f);

    float4 w2a  = *(const float4*)(W2  + l16 * 4);
    float4 w2b  = *(const float4*)(W2  + HH + l16 * 4);
    float4 wf2a = *(const float4*)(Wf2 + l16 * 4);
    float4 wf2b = *(const float4*)(Wf2 + HH + l16 * 4);

    float zp = h0.x * w2a.x + h0.y * w2a.y + h0.z * w2a.z + h0.w * w2a.w
             + h1.x * w2b.x + h1.y * w2b.y + h1.z * w2b.z + h1.w * w2b.w;
    float fp = h0.x * wf2a.x + h0.y * wf2a.y + h0.z * wf2a.z + h0.w * wf2a.w
             + h1.x * wf2b.x + h1.y * wf2b.y + h1.z * wf2b.z + h1.w * wf2b.w;
#pragma unroll
    for (int o = 8; o > 0; o >>= 1) {
        zp += __shfl_xor(zp, o, 64);
        fp += __shfl_xor(fp, o, 64);
    }
    if (lane == 0 && wid < N) {
        z[i]   = zp;
        out[i] = fp + b2[0] + bf2[0];
    }
}

// ------------------------------------------- layer-2 aggregate (CSR) --------
// out[i] += di * ( sum_j z[r_j]*dinv[r_j]  +  z[i]*di )
__global__ __launch_bounds__(256) void k_agg2(
    const int* __restrict__ off, const int* __restrict__ cnt,
    const int* __restrict__ sedge, const float* __restrict__ dinv,
    const float* __restrict__ z, float* __restrict__ out, int N)
{
    const int wid  = (blockIdx.x * blockDim.x + threadIdx.x) >> 6;
    const int lane = threadIdx.x & 63;
    const int g    = lane >> 4;
    const int l16  = lane & 15;
    int i = wid * 4 + g;
    bool ok = (i < N);
    i = ok ? i : (N - 1);

    const int jb = off[i], je = jb + cnt[i];
    float s = 0.0f;
    for (int j = jb + l16; j < je; j += 16) {
        int r = sedge[j];
        s = fmaf(z[r], dinv[r], s);
    }
#pragma unroll
    for (int o = 8; o > 0; o >>= 1) s += __shfl_xor(s, o, 64);
    if (l16 == 0 && ok) {
        float di = dinv[i];
        out[i] += di * fmaf(z[i], di, s);
    }
}

// ---------------------------------------------------------------- launch ----
extern "C" void kernel_launch(void* const* d_in, const int* in_sizes, int n_in,
                              void* d_out, int out_size, void* d_ws, size_t ws_size,
                              hipStream_t stream)
{
    const float* x   = (const float*)d_in[0];
    const int*   ei  = (const int*)d_in[1];    // [2,E]: row=ei[e], col=ei[E+e]
    const float* W1  = (const float*)d_in[2];
    const float* b1  = (const float*)d_in[3];
    const float* Wf1 = (const float*)d_in[4];
    const float* bf1 = (const float*)d_in[5];
    const float* W2  = (const float*)d_in[6];
    const float* b2  = (const float*)d_in[7];
    const float* Wf2 = (const float*)d_in[8];
    const float* bf2 = (const float*)d_in[9];

    const int N = in_sizes[0] / FIN;   // 100000
    const int E = in_sizes[1] / 2;     // 1600000
    const int NB = (N + NPB - 1) / NPB;  // 391 buckets
    float* out = (float*)d_out;

    // workspace layout (4-byte units):
    // xw[N*128] | dinv[N] | z[N] | cnt[N] | bcur[MAXNB] | bbase[MAXNB] |
    // off[N] | sedge int[E] | xwh[N*64 halves].
    // binned[NB*BCAP int2] overlays xw (consumed by k_place before k_gemm).
    float* ws   = (float*)d_ws;
    float* xw   = ws;
    float* dinv = xw + (size_t)N * FIN;
    float* z    = dinv + N;
    int*   cnt  = (int*)(z + N);
    int*   bcur = cnt + N;
    int*   bbase = bcur + MAXNB;
    int*   off  = bbase + MAXNB;
    int*   sedge = off + N;
    _Float16* xwh = (_Float16*)(sedge + E);
    int2*  binned = (int2*)ws;             // overlay on xw region

    hipMemsetAsync(bcur, 0, (size_t)MAXNB * sizeof(int), stream);

    k_bin<<<(E + BCH - 1) / BCH, 256, 0, stream>>>(ei, bcur, binned, E, NB);
    k_bscan<<<1, 64, 0, stream>>>(bcur, bbase, NB);
    k_place<<<NB, 256, 0, stream>>>(binned, bcur, bbase, cnt, off, dinv, sedge, N);

    k_gemm<<<(N + 63) / 64, 256, 0, stream>>>(x, W1, Wf1, xw, xwh, N);

    {
        long threads = (long)N * 64;           // one wave per node
        int blocks = (int)((threads + 255) / 256);
        k_fused<<<blocks, 256, 0, stream>>>(off, cnt, sedge, dinv, xw, xwh,
                                            b1, bf1, W2, Wf2, b2, bf2, z, out, N);
    }

    {
        long waves = ((long)N + 3) / 4;        // one wave per 4 nodes
        int blocks = (int)((waves * 64 + 255) / 256);
        k_agg2<<<blocks, 256, 0, stream>>>(off, cnt, sedge, dinv, z, out, N);
    }
}

// Round 15
// 250.882 us; speedup vs baseline: 1.3231x; 1.0945x over previous
//
#include <hip/hip_runtime.h>
#include <hip/hip_fp16.h>

constexpr int FIN   = 128;   // input features (also total hidden width)
constexpr int HH    = 64;    // half hidden (GCN branch width)
constexpr int NPB   = 256;   // nodes per bucket (bucket = col >> 8)
constexpr int MAXNB = 512;   // max buckets supported (N <= 131072)
constexpr int BCH   = 4096;  // edges per k_bin block
constexpr int BCAP  = 4608;  // bucket stride in binned[]
constexpr int CAPB  = 4500;  // LDS stage capacity in k_place

typedef _Float16 half4v __attribute__((ext_vector_type(4)));

// ------------------------------------------------------------------ GEMM ----
// xwh[N,128] = fp16( x[N,128] @ [W1 | Wf1] )  — fp16 is the sole post-GEMM
// representation (fp32 xw removed: k_fused's 51.2MB fp32 self/skip read was
// ~43% of its FETCH; fp16 rounding there adds ~5e-4, negligible vs the
// existing fp16-gather error).
__global__ __launch_bounds__(256) void k_gemm(
    const float* __restrict__ x, const float* __restrict__ W1,
    const float* __restrict__ Wf1, _Float16* __restrict__ xwh, int N)
{
    __shared__ float xs[16][68];     // [k][node], +4 pad
    __shared__ float ws[16][128];    // [k][col]

    const int tid = threadIdx.x;
    const int tx  = tid & 31;
    const int ty  = tid >> 5;
    const int nbase = blockIdx.x * 64;

    float acc[8][4];
#pragma unroll
    for (int i = 0; i < 8; ++i)
#pragma unroll
        for (int j = 0; j < 4; ++j) acc[i][j] = 0.0f;

    const int xr_row = tid >> 2;
    const int xr_kk0 = (tid & 3) * 4;
    int nload = nbase + xr_row;
    const int nclamped = (nload < N) ? nload : (N - 1);

    const int wk = tid >> 4;
    const int wc = (tid * 8) & 127;

    for (int k0 = 0; k0 < FIN; k0 += 16) {
        float4 xv = *(const float4*)(x + (size_t)nclamped * FIN + k0 + xr_kk0);
        xs[xr_kk0 + 0][xr_row] = xv.x;
        xs[xr_kk0 + 1][xr_row] = xv.y;
        xs[xr_kk0 + 2][xr_row] = xv.z;
        xs[xr_kk0 + 3][xr_row] = xv.w;
        {
            const float* src = (wc < HH) ? (W1  + (size_t)(k0 + wk) * HH + wc)
                                         : (Wf1 + (size_t)(k0 + wk) * HH + (wc - HH));
            float4 w0 = *(const float4*)(src);
            float4 w1 = *(const float4*)(src + 4);
            *(float4*)&ws[wk][wc]     = w0;
            *(float4*)&ws[wk][wc + 4] = w1;
        }
        __syncthreads();

#pragma unroll
        for (int kk = 0; kk < 16; ++kk) {
            float4 xa = *(const float4*)&xs[kk][ty * 8];
            float4 xb = *(const float4*)&xs[kk][ty * 8 + 4];
            float4 wv = *(const float4*)&ws[kk][tx * 4];
            float xr[8] = {xa.x, xa.y, xa.z, xa.w, xb.x, xb.y, xb.z, xb.w};
#pragma unroll
            for (int i = 0; i < 8; ++i) {
                acc[i][0] = fmaf(xr[i], wv.x, acc[i][0]);
                acc[i][1] = fmaf(xr[i], wv.y, acc[i][1]);
                acc[i][2] = fmaf(xr[i], wv.z, acc[i][2]);
                acc[i][3] = fmaf(xr[i], wv.w, acc[i][3]);
            }
        }
        __syncthreads();
    }

#pragma unroll
    for (int i = 0; i < 8; ++i) {
        int n = nbase + ty * 8 + i;
        if (n < N) {
            half4v h;
            h[0] = (_Float16)acc[i][0]; h[1] = (_Float16)acc[i][1];
            h[2] = (_Float16)acc[i][2]; h[3] = (_Float16)acc[i][3];
            *(half4v*)(xwh + (size_t)n * FIN + tx * 4) = h;
        }
    }
}

// --------------------------------------- pass A: bin edges by bucket --------
// LDS-reorders each 4096-edge chunk by bucket (col>>8) and flushes runs to
// per-bucket regions of binned[]. No per-edge global atomics.
__global__ __launch_bounds__(256) void k_bin(
    const int* __restrict__ ei, int* __restrict__ bcur,
    int2* __restrict__ binned, int E, int NB)
{
    __shared__ int hist[MAXNB], scur[MAXNB], gbase[MAXNB], sbase[MAXNB];
    __shared__ int ssum[256];
    __shared__ int2 st[BCH];
    const int tid = threadIdx.x;
    const int e0  = blockIdx.x * BCH;
    const int nE  = min(BCH, E - e0);

    for (int b = tid; b < NB; b += 256) hist[b] = 0;
    __syncthreads();

    for (int k = tid; k < nE; k += 256)
        atomicAdd(&hist[ei[E + e0 + k] >> 8], 1);
    __syncthreads();

    // exclusive scan hist -> sbase (2 elems/thread over padded 512)
    int h0 = (2 * tid     < NB) ? hist[2 * tid]     : 0;
    int h1 = (2 * tid + 1 < NB) ? hist[2 * tid + 1] : 0;
    ssum[tid] = h0 + h1;
    __syncthreads();
    for (int o = 1; o < 256; o <<= 1) {
        int y = (tid >= o) ? ssum[tid - o] : 0;
        __syncthreads();
        ssum[tid] += y;
        __syncthreads();
    }
    int eb = ssum[tid] - h0 - h1;
    if (2 * tid     < NB) { sbase[2 * tid]     = eb;      scur[2 * tid]     = eb; }
    if (2 * tid + 1 < NB) { sbase[2 * tid + 1] = eb + h0; scur[2 * tid + 1] = eb + h0; }
    __syncthreads();

    // claim global per-bucket ranges (one atomic per non-empty bucket)
    for (int b = tid; b < NB; b += 256)
        if (hist[b] > 0) gbase[b] = atomicAdd(bcur + b, hist[b]);

    // LDS reorder by bucket
    for (int k = tid; k < nE; k += 256) {
        int r = ei[e0 + k];
        int c = ei[E + e0 + k];
        int s = atomicAdd(&scur[c >> 8], 1);
        st[s] = make_int2(r, c);
    }
    __syncthreads();

    // coalesced-run flush (bucket recomputed from col)
    for (int s = tid; s < nE; s += 256) {
        int2 rc = st[s];
        int b = rc.y >> 8;
        long dest = (long)b * BCAP + gbase[b] + (s - sbase[b]);
        binned[dest] = rc;
    }
}

// ------------------- parallel scan: bucket totals -> bucket bases -----------
// (serial 1-thread loop replaced: 391 dependent-latency iterations on one
// lane was a potential hidden 10-40us)
__global__ __launch_bounds__(256) void k_bscan(
    const int* __restrict__ bcur, int* __restrict__ bbase, int NB)
{
    __shared__ int s[256];
    const int t = threadIdx.x;
    int a = (2 * t     < NB) ? bcur[2 * t]     : 0;
    int b = (2 * t + 1 < NB) ? bcur[2 * t + 1] : 0;
    s[t] = a + b;
    __syncthreads();
    for (int o = 1; o < 256; o <<= 1) {
        int y = (t >= o) ? s[t - o] : 0;
        __syncthreads();
        s[t] += y;
        __syncthreads();
    }
    int excl = s[t] - a - b;
    if (2 * t     < NB) bbase[2 * t]     = excl;
    if (2 * t + 1 < NB) bbase[2 * t + 1] = excl + a;
}

// ---------------- pass B: per-bucket degree+scan+place, coalesced write -----
__global__ __launch_bounds__(256) void k_place(
    const int2* __restrict__ binned, const int* __restrict__ bcur,
    const int* __restrict__ bbase, int* __restrict__ cnt, int* __restrict__ off,
    float* __restrict__ dinv, int* __restrict__ sedge, int N)
{
    const int b   = blockIdx.x;
    const int tid = threadIdx.x;
    const int nlo = b << 8;
    const int nn  = min(NPB, N - nlo);
    __shared__ int lcnt[NPB], loff[NPB], lscan[NPB];
    __shared__ int stage[CAPB];
    lcnt[tid] = 0;
    __syncthreads();
    const int ke = bcur[b];
    const int2* src = binned + (long)b * BCAP;
    // pass 1: per-node degree
    for (int k = tid; k < ke; k += 256)
        atomicAdd(&lcnt[src[k].y - nlo], 1);
    __syncthreads();
    // exclusive scan of lcnt[256]
    int v = lcnt[tid];
    lscan[tid] = v;
    __syncthreads();
    for (int o = 1; o < 256; o <<= 1) {
        int y = (tid >= o) ? lscan[tid - o] : 0;
        __syncthreads();
        lscan[tid] += y;
        __syncthreads();
    }
    int excl = lscan[tid] - v;
    loff[tid] = excl;
    const int base = bbase[b];
    if (tid < nn) {
        cnt[nlo + tid]  = v;
        off[nlo + tid]  = base + excl;
        dinv[nlo + tid] = rsqrtf((float)v + 1.0f);
    }
    lcnt[tid] = 0;
    __syncthreads();
    // pass 2: place source ids
    if (ke <= CAPB) {
        for (int k = tid; k < ke; k += 256) {
            int2 rc = src[k];
            int li = rc.y - nlo;
            int p = atomicAdd(&lcnt[li], 1);
            stage[loff[li] + p] = rc.x;
        }
        __syncthreads();
        for (int s = tid; s < ke; s += 256) sedge[base + s] = stage[s];
    } else {   // statistically impossible overflow fallback
        for (int k = tid; k < ke; k += 256) {
            int2 rc = src[k];
            int li = rc.y - nlo;
            int p = atomicAdd(&lcnt[li], 1);
            sedge[base + loff[li] + p] = rc.x;
        }
    }
}

// ------------------------- fused: layer-1 aggregate + relu + layer-2 dots ---
// all feature reads fp16 from xwh[N][128]; norm = dinv[r]*dinv[i] recomputed.
__global__ __launch_bounds__(256) void k_fused(
    const int* __restrict__ off, const int* __restrict__ cnt,
    const int* __restrict__ sedge, const float* __restrict__ dinv,
    const _Float16* __restrict__ xwh,
    const float* __restrict__ b1, const float* __restrict__ bf1,
    const float* __restrict__ W2, const float* __restrict__ Wf2,
    const float* __restrict__ b2, const float* __restrict__ bf2,
    float* __restrict__ z, float* __restrict__ out, int N)
{
    const int wid  = (blockIdx.x * blockDim.x + threadIdx.x) >> 6;  // node id
    const int lane = threadIdx.x & 63;
    const int g    = lane >> 4;        // edge group 0..3
    const int l16  = lane & 15;        // feature quad
    const int i    = (wid < N) ? wid : (N - 1);

    const int jb  = off[i];
    const int deg = cnt[i];
    const float di = dinv[i];

    int   er_r = i;
    float er_d = 0.0f;
    if (lane < deg) { er_r = sedge[jb + lane]; er_d = dinv[er_r]; }

    float4 acc = make_float4(0.f, 0.f, 0.f, 0.f);
    const int lim = (deg < 64) ? deg : 64;
    for (int t0 = 0; t0 < lim; t0 += 8) {
        int  ttA   = t0 + g;
        int  ttB   = t0 + 4 + g;
        bool vA    = ttA < lim;
        bool vB    = ttB < lim;
        int   rowA = __shfl(er_r, ttA, 64);
        float dA   = __shfl(er_d, ttA, 64);
        int   rowB = __shfl(er_r, ttB, 64);
        float dB   = __shfl(er_d, ttB, 64);
        rowA       = vA ? rowA : i;
        rowB       = vB ? rowB : i;
        float sA   = vA ? dA * di : 0.0f;
        float sB   = vB ? dB * di : 0.0f;
        half4v a = *(const half4v*)(xwh + (size_t)rowA * FIN + l16 * 4);
        half4v b = *(const half4v*)(xwh + (size_t)rowB * FIN + l16 * 4);
        acc.x = fmaf((float)a[0], sA, acc.x);
        acc.y = fmaf((float)a[1], sA, acc.y);
        acc.z = fmaf((float)a[2], sA, acc.z);
        acc.w = fmaf((float)a[3], sA, acc.w);
        acc.x = fmaf((float)b[0], sB, acc.x);
        acc.y = fmaf((float)b[1], sB, acc.y);
        acc.z = fmaf((float)b[2], sB, acc.z);
        acc.w = fmaf((float)b[3], sB, acc.w);
    }
    // rare tail: deg > 64
    for (int j = jb + 64 + g; j < jb + deg; j += 4) {
        int rj = sedge[j];
        float s = dinv[rj] * di;
        half4v v = *(const half4v*)(xwh + (size_t)rj * FIN + l16 * 4);
        acc.x = fmaf((float)v[0], s, acc.x);
        acc.y = fmaf((float)v[1], s, acc.y);
        acc.z = fmaf((float)v[2], s, acc.z);
        acc.w = fmaf((float)v[3], s, acc.w);
    }

    // combine the 4 edge-groups
    acc.x += __shfl_xor(acc.x, 16, 64); acc.x += __shfl_xor(acc.x, 32, 64);
    acc.y += __shfl_xor(acc.y, 16, 64); acc.y += __shfl_xor(acc.y, 32, 64);
    acc.z += __shfl_xor(acc.z, 16, 64); acc.z += __shfl_xor(acc.z, 32, 64);
    acc.w += __shfl_xor(acc.w, 16, 64); acc.w += __shfl_xor(acc.w, 32, 64);

    // self loop (fp16 row)
    float dd = di * di;
    half4v svh = *(const half4v*)(xwh + (size_t)i * FIN + l16 * 4);
    acc.x = fmaf((float)svh[0], dd, acc.x);
    acc.y = fmaf((float)svh[1], dd, acc.y);
    acc.z = fmaf((float)svh[2], dd, acc.z);
    acc.w = fmaf((float)svh[3], dd, acc.w);

    // epilogue: relu + two 128-dots
    float4 b1v  = *(const float4*)(b1  + l16 * 4);
    float4 bf1v = *(const float4*)(bf1 + l16 * 4);
    half4v x1h  = *(const half4v*)(xwh + (size_t)i * FIN + HH + l16 * 4);
    float4 h0, h1;
    h0.x = fmaxf(acc.x + b1v.x, 0.f);  h0.y = fmaxf(acc.y + b1v.y, 0.f);
    h0.z = fmaxf(acc.z + b1v.z, 0.f);  h0.w = fmaxf(acc.w + b1v.w, 0.f);
    h1.x = fmaxf((float)x1h[0] + bf1v.x, 0.f);  h1.y = fmaxf((float)x1h[1] + bf1v.y, 0.f);
    h1.z = fmaxf((float)x1h[2] + bf1v.z, 0.f);  h1.w = fmaxf((float)x1h[3] + bf1v.w, 0.f);

    float4 w2a  = *(const float4*)(W2  + l16 * 4);
    float4 w2b  = *(const float4*)(W2  + HH + l16 * 4);
    float4 wf2a = *(const float4*)(Wf2 + l16 * 4);
    float4 wf2b = *(const float4*)(Wf2 + HH + l16 * 4);

    float zp = h0.x * w2a.x + h0.y * w2a.y + h0.z * w2a.z + h0.w * w2a.w
             + h1.x * w2b.x + h1.y * w2b.y + h1.z * w2b.z + h1.w * w2b.w;
    float fp = h0.x * wf2a.x + h0.y * wf2a.y + h0.z * wf2a.z + h0.w * wf2a.w
             + h1.x * wf2b.x + h1.y * wf2b.y + h1.z * wf2b.z + h1.w * wf2b.w;
#pragma unroll
    for (int o = 8; o > 0; o >>= 1) {
        zp += __shfl_xor(zp, o, 64);
        fp += __shfl_xor(fp, o, 64);
    }
    if (lane == 0 && wid < N) {
        z[i]   = zp;
        out[i] = fp + b2[0] + bf2[0];
    }
}

// ------------------------------------------- layer-2 aggregate (CSR) --------
// out[i] += di * ( sum_j z[r_j]*dinv[r_j]  +  z[i]*di )
__global__ __launch_bounds__(256) void k_agg2(
    const int* __restrict__ off, const int* __restrict__ cnt,
    const int* __restrict__ sedge, const float* __restrict__ dinv,
    const float* __restrict__ z, float* __restrict__ out, int N)
{
    const int wid  = (blockIdx.x * blockDim.x + threadIdx.x) >> 6;
    const int lane = threadIdx.x & 63;
    const int g    = lane >> 4;
    const int l16  = lane & 15;
    int i = wid * 4 + g;
    bool ok = (i < N);
    i = ok ? i : (N - 1);

    const int jb = off[i], je = jb + cnt[i];
    float s = 0.0f;
    for (int j = jb + l16; j < je; j += 16) {
        int r = sedge[j];
        s = fmaf(z[r], dinv[r], s);
    }
#pragma unroll
    for (int o = 8; o > 0; o >>= 1) s += __shfl_xor(s, o, 64);
    if (l16 == 0 && ok) {
        float di = dinv[i];
        out[i] += di * fmaf(z[i], di, s);
    }
}

// ---------------------------------------------------------------- launch ----
extern "C" void kernel_launch(void* const* d_in, const int* in_sizes, int n_in,
                              void* d_out, int out_size, void* d_ws, size_t ws_size,
                              hipStream_t stream)
{
    const float* x   = (const float*)d_in[0];
    const int*   ei  = (const int*)d_in[1];    // [2,E]: row=ei[e], col=ei[E+e]
    const float* W1  = (const float*)d_in[2];
    const float* b1  = (const float*)d_in[3];
    const float* Wf1 = (const float*)d_in[4];
    const float* bf1 = (const float*)d_in[5];
    const float* W2  = (const float*)d_in[6];
    const float* b2  = (const float*)d_in[7];
    const float* Wf2 = (const float*)d_in[8];
    const float* bf2 = (const float*)d_in[9];

    const int N = in_sizes[0] / FIN;   // 100000
    const int E = in_sizes[1] / 2;     // 1600000
    const int NB = (N + NPB - 1) / NPB;  // 391 buckets
    float* out = (float*)d_out;

    // workspace layout (4-byte units):
    // dinv[N] | z[N] | cnt[N] | bcur[MAXNB] | bbase[MAXNB] | off[N] |
    // sedge int[E] | xwh[N*128 halves] | binned[NB*BCAP int2]
    float* ws   = (float*)d_ws;
    float* dinv = ws;
    float* z    = dinv + N;
    int*   cnt  = (int*)(z + N);
    int*   bcur = cnt + N;
    int*   bbase = bcur + MAXNB;
    int*   off  = bbase + MAXNB;
    int*   sedge = off + N;
    _Float16* xwh = (_Float16*)(sedge + E);
    int2*  binned = (int2*)(xwh + (size_t)N * FIN);

    hipMemsetAsync(bcur, 0, (size_t)MAXNB * sizeof(int), stream);

    k_bin<<<(E + BCH - 1) / BCH, 256, 0, stream>>>(ei, bcur, binned, E, NB);
    k_bscan<<<1, 256, 0, stream>>>(bcur, bbase, NB);
    k_place<<<NB, 256, 0, stream>>>(binned, bcur, bbase, cnt, off, dinv, sedge, N);

    k_gemm<<<(N + 63) / 64, 256, 0, stream>>>(x, W1, Wf1, xwh, N);

    {
        long threads = (long)N * 64;           // one wave per node
        int blocks = (int)((threads + 255) / 256);
        k_fused<<<blocks, 256, 0, stream>>>(off, cnt, sedge, dinv, xwh,
                                            b1, bf1, W2, Wf2, b2, bf2, z, out, N);
    }

    {
        long waves = ((long)N + 3) / 4;        // one wave per 4 nodes
        int blocks = (int)((waves * 64 + 255) / 256);
        k_agg2<<<blocks, 256, 0, stream>>>(off, cnt, sedge, dinv, z, out, N);
    }
}